// Round 8
// baseline (558.130 us; speedup 1.0000x reference)
//
#include <hip/hip_runtime.h>

typedef unsigned short u16;
typedef __bf16 bf16x8 __attribute__((ext_vector_type(8)));
typedef float f32x4 __attribute__((ext_vector_type(4)));

// ---------- helpers ----------
__device__ __forceinline__ u16 f2bf(float f) {
  unsigned u = __float_as_uint(f);
  u += 0x7FFF + ((u >> 16) & 1);   // RNE
  return (u16)(u >> 16);
}

__device__ __forceinline__ unsigned pack2(float lo, float hi) {
  return (unsigned)f2bf(lo) | ((unsigned)f2bf(hi) << 16);
}

__device__ __forceinline__ void gload_lds16(const void* g, void* l) {
  __builtin_amdgcn_global_load_lds(
      (const __attribute__((address_space(1))) void*)g,
      (__attribute__((address_space(3))) void*)l,
      16, 0, 0);
}

// T2 swizzle: XOR row&7 into the 16B-slot bits. Involution, 16B-preserving.
__device__ __forceinline__ int swzb(int lin) {
  return lin ^ (((lin >> 7) & 7) << 4);
}

// ---------- fused prep: x->bf16, Wv->bf16, Wofold = sum_h Wo[:, n+1024h] ----------
__global__ void prep_all(const float4* __restrict__ x, const float* __restrict__ Wv,
                         const float* __restrict__ Wo, uint4* __restrict__ xb,
                         uint4* __restrict__ Wvb, uint4* __restrict__ Wofb) {
  const int nx = (16384 * 4096) / 8;   // 8388608
  const int nw = (1024 * 4096) / 8;    // 524288
  int i = blockIdx.x * blockDim.x + threadIdx.x;
  const int stride = gridDim.x * blockDim.x;
  for (; i < nx + 2 * nw; i += stride) {
    if (i < nx) {
      float4 a = x[(size_t)i * 2], b = x[(size_t)i * 2 + 1];
      xb[i] = make_uint4(pack2(a.x, a.y), pack2(a.z, a.w),
                         pack2(b.x, b.y), pack2(b.z, b.w));
    } else if (i < nx + nw) {
      int j = i - nx;
      const float4* p = (const float4*)Wv + (size_t)j * 2;
      float4 a = p[0], b = p[1];
      Wvb[j] = make_uint4(pack2(a.x, a.y), pack2(a.z, a.w),
                          pack2(b.x, b.y), pack2(b.z, b.w));
    } else {
      int j = i - nx - nw;
      int row = j >> 7;
      int c = (j & 127) * 8;
      float4 s0 = {0.f, 0.f, 0.f, 0.f}, s1 = {0.f, 0.f, 0.f, 0.f};
#pragma unroll
      for (int h = 0; h < 4; ++h) {
        const float4* p = (const float4*)(Wo + (size_t)row * 4096 + h * 1024 + c);
        float4 a = p[0], b = p[1];
        s0.x += a.x; s0.y += a.y; s0.z += a.z; s0.w += a.w;
        s1.x += b.x; s1.y += b.y; s1.z += b.z; s1.w += b.w;
      }
      Wofb[j] = make_uint4(pack2(s0.x, s0.y), pack2(s0.z, s0.w),
                           pack2(s1.x, s1.y), pack2(s1.z, s1.w));
    }
  }
}

// ---------- staging: linear LDS dest, inverse-swizzled global source ----------
__device__ __forceinline__ void stage_half(const char* g, int ldb, char* ldsTile,
                                           int regionBase, int tid) {
#pragma unroll
  for (int j = 0; j < 2; ++j) {
    const int un = regionBase + j * 8192 + (tid >> 6) * 1024;  // wave-uniform
    const int l  = swzb(un + (tid & 63) * 16);                 // per-lane logical byte
    gload_lds16(g + (size_t)(l >> 7) * (size_t)ldb + (l & 127), ldsTile + un);
  }
}

// which=0 -> rows [0,64)+[128,192); which=1 -> [64,128)+[192,256)
__device__ __forceinline__ void stage_Ahalf(const char* g, int ldb, char* ldsA,
                                            int which, int tid) {
#pragma unroll
  for (int j = 0; j < 2; ++j) {
    const int un = (which ? 8192 : 0) + j * 16384 + (tid >> 6) * 1024;
    const int l  = swzb(un + (tid & 63) * 16);
    gload_lds16(g + (size_t)(l >> 7) * (size_t)ldb + (l & 127), ldsA + un);
  }
}

// ---------- one phase: ds_read A quarter, stage, barrier, lgkm, MFMA ----------
// (R3/R7-verified skeleton — DO NOT restructure; all deviations regressed)
template<int P, class Stage>
__device__ __forceinline__ void do_phase(f32x4 (&acc)[8][4], const bf16x8 (&bfr)[4][2],
                                         const char* sA, const int wrow, const int lm,
                                         const int hi16, const int axor, Stage&& stage) {
  bf16x8 afr[2][2];
#pragma unroll
  for (int m2 = 0; m2 < 2; ++m2)
#pragma unroll
    for (int kk = 0; kk < 2; ++kk) {
      const int row = wrow * 128 + (P * 2 + m2) * 16 + lm;
      afr[m2][kk] = *(const bf16x8*)(sA + ((row * 128 + kk * 64 + hi16) ^ axor));
    }
  stage();
  __builtin_amdgcn_s_barrier();
  asm volatile("s_waitcnt lgkmcnt(0)" ::: "memory");
  __builtin_amdgcn_s_setprio(1);
#pragma unroll
  for (int kk = 0; kk < 2; ++kk)
#pragma unroll
    for (int m2 = 0; m2 < 2; ++m2)
#pragma unroll
      for (int ni = 0; ni < 4; ++ni)
        acc[P * 2 + m2][ni] = __builtin_amdgcn_mfma_f32_16x16x32_bf16(
            afr[m2][kk], bfr[ni][kk], acc[P * 2 + m2][ni], 0, 0, 0);
  __builtin_amdgcn_s_setprio(0);
}

// ---------- persistent uniform-chain 256x256 NT GEMM: C[M,N] = A[M,K] * B[N,K]^T ----
// Grid MUST be 256 blocks x 512 threads. One prologue; staging flows across rep
// boundaries; C-store + acc-reset inline at g % NT == NT-1. NT even, pow2.
template<bool OUT_BF16, int REPS, int NT, int NBN, int NN, int KK>
__global__ __launch_bounds__(512, 2) void gemm256(
    const u16* __restrict__ A, const u16* __restrict__ B, void* __restrict__ Cv) {
  extern __shared__ char smem[];   // 131072 bytes
  constexpr int ldb = KK * 2;      // bytes per row (K-contiguous)
  constexpr int total = REPS * NT;

  const int tid  = threadIdx.x;
  const int lane = tid & 63;
  const int wave = tid >> 6;
  const int wrow = wave >> 2;      // 0..1
  const int wcol = wave & 3;       // 0..3
  const int lm   = lane & 15;
  const int hi16 = (lane >> 4) * 16;
  const int axor = (lm & 7) << 4;

  // T1: bijective XCD swizzle over the 256-block grid (per-XCD chunk = 32)
  const int swzid = (blockIdx.x & 7) * 32 + (blockIdx.x >> 3);

  // panel base for global tile g (pow2 div/mod -> shifts)
  auto panA = [&](int g) -> const char* {
    const int id = (g / NT) * 256 + swzid;
    return (const char*)A + (size_t)(id / NBN) * (size_t)(256 * ldb) +
           (size_t)(g % NT) * 128;
  };
  auto panB = [&](int g) -> const char* {
    const int id = (g / NT) * 256 + swzid;
    return (const char*)B + (size_t)(id % NBN) * (size_t)(256 * ldb) +
           (size_t)(g % NT) * 128;
  };

  f32x4 acc[8][4];
#pragma unroll
  for (int m = 0; m < 8; ++m)
#pragma unroll
    for (int n = 0; n < 4; ++n) acc[m][n] = {0.f, 0.f, 0.f, 0.f};

  // ---- single prologue: tile0 full (8 loads/thr), tile1 B0,B1,A0 (6) ----
  {
    char* s0A = smem;            char* s0B = smem + 32768;
    char* s1A = smem + 65536;    char* s1B = s1A + 32768;
    const char* pA0 = panA(0);   const char* pB0 = panB(0);
    stage_half (pB0, ldb, s0B, 0, tid);
    stage_half (pB0, ldb, s0B, 16384, tid);
    stage_Ahalf(pA0, ldb, s0A, 0, tid);
    stage_Ahalf(pA0, ldb, s0A, 1, tid);
    const char* pA1 = panA(1);   const char* pB1 = panB(1);
    stage_half (pB1, ldb, s1B, 0, tid);
    stage_half (pB1, ldb, s1B, 16384, tid);
    stage_Ahalf(pA1, ldb, s1A, 0, tid);
    asm volatile("s_waitcnt vmcnt(6)" ::: "memory");
    __builtin_amdgcn_s_barrier();
  }

  // ---- main chain: 4 phases per K-tile, counted vmcnt(6), never drain ----
#pragma unroll 1
  for (int g = 0; g < total; ++g) {
    char* sA = smem + (g & 1) * 65536;
    char* sB = sA + 32768;
    char* oA = smem + ((g & 1) ^ 1) * 65536;
    const bool c1 = g + 1 < total, c2 = g + 2 < total;
    const char* Ag1 = panA(g + 1);
    const char* Ag2 = panA(g + 2);
    const char* Bg2 = panB(g + 2);

    // B fragments for the whole tile (8 x ds_read_b128), held in regs
    bf16x8 bfr[4][2];
#pragma unroll
    for (int ni = 0; ni < 4; ++ni)
#pragma unroll
      for (int kk = 0; kk < 2; ++kk) {
        const int row = wcol * 64 + ni * 16 + lm;
        bfr[ni][kk] = *(const bf16x8*)(sB + ((row * 128 + kk * 64 + hi16) ^ axor));
      }

    do_phase<0>(acc, bfr, sA, wrow, lm, hi16, axor,
                [&] { if (c1) stage_Ahalf(Ag1, ldb, oA, 1, tid); });
    __builtin_amdgcn_s_barrier();
    do_phase<1>(acc, bfr, sA, wrow, lm, hi16, axor,
                [&] { if (c2) stage_half(Bg2, ldb, sB, 0, tid); });
    __builtin_amdgcn_s_barrier();
    do_phase<2>(acc, bfr, sA, wrow, lm, hi16, axor,
                [&] { if (c2) stage_half(Bg2, ldb, sB, 16384, tid); });
    __builtin_amdgcn_s_barrier();
    do_phase<3>(acc, bfr, sA, wrow, lm, hi16, axor,
                [&] { if (c2) stage_Ahalf(Ag2, ldb, sA, 0, tid); });
    if (c2)      asm volatile("s_waitcnt vmcnt(6)" ::: "memory");
    else if (c1) asm volatile("s_waitcnt vmcnt(0)" ::: "memory");
    __builtin_amdgcn_s_barrier();

    // ---- rep boundary: store C tile, reset acc; staging for next rep is
    // already in flight (stores drain to L2 at the next vmcnt — cheap) ----
    if ((g & (NT - 1)) == (NT - 1)) {
      const int id = (g / NT) * 256 + swzid;
      const long rowb = (long)(id / NBN) * 256 + wrow * 128 + ((lane >> 4) * 4);
      const long colb = (long)(id % NBN) * 256 + wcol * 64 + lm;
#pragma unroll
      for (int m = 0; m < 8; ++m)
#pragma unroll
        for (int ni = 0; ni < 4; ++ni)
#pragma unroll
          for (int r = 0; r < 4; ++r) {
            const long idx = (rowb + m * 16 + r) * NN + colb + ni * 16;
            if constexpr (OUT_BF16) ((u16*)Cv)[idx] = f2bf(acc[m][ni][r]);
            else                    ((float*)Cv)[idx] = acc[m][ni][r];
          }
#pragma unroll
      for (int m = 0; m < 8; ++m)
#pragma unroll
        for (int n = 0; n < 4; ++n) acc[m][n] = {0.f, 0.f, 0.f, 0.f};
    }
  }
}

// ---------- launch ----------
extern "C" void kernel_launch(void* const* d_in, const int* in_sizes, int n_in,
                              void* d_out, int out_size, void* d_ws, size_t ws_size,
                              hipStream_t stream) {
  const float* x  = (const float*)d_in[0];
  // d_in[1] = Wq (dead), d_in[2] = Wk (dead), d_in[5] = mask (dead)
  const float* Wv = (const float*)d_in[3];
  const float* Wo = (const float*)d_in[4];

  const int M = 16384;   // B*S
  const int D = 4096;    // DIM
  const int R = 1024;    // KV_RANK

  u16* vb   = (u16*)d_ws;
  u16* Wvb  = vb + (size_t)M * R;
  u16* Wofb = Wvb + (size_t)R * D;
  u16* xb   = (u16*)d_out;   // dead by the time GEMM2 writes d_out

  (void)hipFuncSetAttribute((const void*)gemm256<true, 1, 64, 4, 1024, 4096>,
                            hipFuncAttributeMaxDynamicSharedMemorySize, 131072);
  (void)hipFuncSetAttribute((const void*)gemm256<false, 4, 16, 16, 4096, 1024>,
                            hipFuncAttributeMaxDynamicSharedMemorySize, 131072);

  prep_all<<<dim3(2048), dim3(256), 0, stream>>>((const float4*)x, Wv, Wo,
                                                 (uint4*)xb, (uint4*)Wvb, (uint4*)Wofb);
  // v = x @ Wv^T   (M=16384, N=1024, K=4096): 64 tiles, REPS=1 (schedule == R7)
  gemm256<true, 1, 64, 4, 1024, 4096>
      <<<dim3(256), dim3(512), 131072, stream>>>(xb, Wvb, vb);
  // out = v @ Wofold^T (M=16384, N=4096, K=1024): 4 reps x 16 tiles, uniform chain
  gemm256<false, 4, 16, 16, 4096, 1024>
      <<<dim3(256), dim3(512), 131072, stream>>>(vb, Wofb, (float*)d_out);
}

// Round 9
// 363.844 us; speedup vs baseline: 1.5340x; 1.5340x over previous
//
#include <hip/hip_runtime.h>

typedef unsigned short u16;
typedef __bf16 bf16x8 __attribute__((ext_vector_type(8)));
typedef float f32x4 __attribute__((ext_vector_type(4)));

// ---------- helpers ----------
__device__ __forceinline__ u16 f2bf(float f) {
  unsigned u = __float_as_uint(f);
  u += 0x7FFF + ((u >> 16) & 1);   // RNE
  return (u16)(u >> 16);
}

__device__ __forceinline__ unsigned pack2(float lo, float hi) {
  return (unsigned)f2bf(lo) | ((unsigned)f2bf(hi) << 16);
}

__device__ __forceinline__ void gload_lds16(const void* g, void* l) {
  __builtin_amdgcn_global_load_lds(
      (const __attribute__((address_space(1))) void*)g,
      (__attribute__((address_space(3))) void*)l,
      16, 0, 0);
}

// T2 swizzle: XOR row&7 into the 16B-slot bits. Involution, 16B-preserving.
__device__ __forceinline__ int swzb(int lin) {
  return lin ^ (((lin >> 7) & 7) << 4);
}

// ---------- fused prep: x->bf16, Wv->bf16, Wofold = sum_h Wo[:, n+1024h] ----------
__global__ void prep_all(const float4* __restrict__ x, const float* __restrict__ Wv,
                         const float* __restrict__ Wo, uint4* __restrict__ xb,
                         uint4* __restrict__ Wvb, uint4* __restrict__ Wofb) {
  const int nx = (16384 * 4096) / 8;   // 8388608
  const int nw = (1024 * 4096) / 8;    // 524288
  int i = blockIdx.x * blockDim.x + threadIdx.x;
  const int stride = gridDim.x * blockDim.x;
  for (; i < nx + 2 * nw; i += stride) {
    if (i < nx) {
      float4 a = x[(size_t)i * 2], b = x[(size_t)i * 2 + 1];
      xb[i] = make_uint4(pack2(a.x, a.y), pack2(a.z, a.w),
                         pack2(b.x, b.y), pack2(b.z, b.w));
    } else if (i < nx + nw) {
      int j = i - nx;
      const float4* p = (const float4*)Wv + (size_t)j * 2;
      float4 a = p[0], b = p[1];
      Wvb[j] = make_uint4(pack2(a.x, a.y), pack2(a.z, a.w),
                          pack2(b.x, b.y), pack2(b.z, b.w));
    } else {
      int j = i - nx - nw;
      int row = j >> 7;
      int c = (j & 127) * 8;
      float4 s0 = {0.f, 0.f, 0.f, 0.f}, s1 = {0.f, 0.f, 0.f, 0.f};
#pragma unroll
      for (int h = 0; h < 4; ++h) {
        const float4* p = (const float4*)(Wo + (size_t)row * 4096 + h * 1024 + c);
        float4 a = p[0], b = p[1];
        s0.x += a.x; s0.y += a.y; s0.z += a.z; s0.w += a.w;
        s1.x += b.x; s1.y += b.y; s1.z += b.z; s1.w += b.w;
      }
      Wofb[j] = make_uint4(pack2(s0.x, s0.y), pack2(s0.z, s0.w),
                           pack2(s1.x, s1.y), pack2(s1.z, s1.w));
    }
  }
}

// ---------- staging: linear LDS dest, inverse-swizzled global source ----------
__device__ __forceinline__ void stage_half(const char* g, int ldb, char* ldsTile,
                                           int regionBase, int tid) {
#pragma unroll
  for (int j = 0; j < 2; ++j) {
    const int un = regionBase + j * 8192 + (tid >> 6) * 1024;  // wave-uniform
    const int l  = swzb(un + (tid & 63) * 16);                 // per-lane logical byte
    gload_lds16(g + (size_t)(l >> 7) * (size_t)ldb + (l & 127), ldsTile + un);
  }
}

// which=0 -> rows [0,64)+[128,192); which=1 -> [64,128)+[192,256)
__device__ __forceinline__ void stage_Ahalf(const char* g, int ldb, char* ldsA,
                                            int which, int tid) {
#pragma unroll
  for (int j = 0; j < 2; ++j) {
    const int un = (which ? 8192 : 0) + j * 16384 + (tid >> 6) * 1024;
    const int l  = swzb(un + (tid & 63) * 16);
    gload_lds16(g + (size_t)(l >> 7) * (size_t)ldb + (l & 127), ldsA + un);
  }
}

// ---------- one phase: ds_read A quarter, stage, barrier, lgkm, MFMA ----------
// (R3/R7-verified skeleton — DO NOT restructure; all deviations regressed)
template<int P, class Stage>
__device__ __forceinline__ void do_phase(f32x4 (&acc)[8][4], const bf16x8 (&bfr)[4][2],
                                         const char* sA, const int wrow, const int lm,
                                         const int hi16, const int axor, Stage&& stage) {
  bf16x8 afr[2][2];
#pragma unroll
  for (int m2 = 0; m2 < 2; ++m2)
#pragma unroll
    for (int kk = 0; kk < 2; ++kk) {
      const int row = wrow * 128 + (P * 2 + m2) * 16 + lm;
      afr[m2][kk] = *(const bf16x8*)(sA + ((row * 128 + kk * 64 + hi16) ^ axor));
    }
  stage();
  __builtin_amdgcn_s_barrier();
  asm volatile("s_waitcnt lgkmcnt(0)" ::: "memory");
  __builtin_amdgcn_s_setprio(1);
#pragma unroll
  for (int kk = 0; kk < 2; ++kk)
#pragma unroll
    for (int m2 = 0; m2 < 2; ++m2)
#pragma unroll
      for (int ni = 0; ni < 4; ++ni)
        acc[P * 2 + m2][ni] = __builtin_amdgcn_mfma_f32_16x16x32_bf16(
            afr[m2][kk], bfr[ni][kk], acc[P * 2 + m2][ni], 0, 0, 0);
  __builtin_amdgcn_s_setprio(0);
}

// ---------- persistent 256x256 8-phase NT GEMM: C[M,N] = A[M,K] * B[N,K]^T ----------
// Grid MUST be 256 blocks of 512 threads. Each block computes REPS output tiles.
template<bool OUT_BF16, int REPS>
__global__ __launch_bounds__(512, 2) void gemm256(
    const u16* __restrict__ A, const u16* __restrict__ B, void* __restrict__ Cv,
    int M, int N, int K) {
  extern __shared__ char smem[];   // 131072 bytes

  const int tid  = threadIdx.x;
  const int lane = tid & 63;
  const int wave = tid >> 6;
  const int wrow = wave >> 2;      // 0..1
  const int wcol = wave & 3;       // 0..3
  const int lm   = lane & 15;
  const int hi16 = (lane >> 4) * 16;
  const int axor = (lm & 7) << 4;

  // T1: bijective XCD swizzle over a 256-block grid (per-XCD chunk = 32)
  const int swzid = (blockIdx.x & 7) * 32 + (blockIdx.x >> 3);
  const int nbn = N >> 8;
  const int ldb = K * 2;
  const int nt  = K >> 6;

#pragma unroll 1
  for (int rep = 0; rep < REPS; ++rep) {
    const int id = rep * 256 + swzid;
    const int bm = id / nbn, bn = id % nbn;
    const char* Ab = (const char*)A + (size_t)bm * 256 * (size_t)ldb;
    const char* Bb = (const char*)B + (size_t)bn * 256 * (size_t)ldb;

    f32x4 acc[8][4];
#pragma unroll
    for (int m = 0; m < 8; ++m)
#pragma unroll
      for (int n = 0; n < 4; ++n) acc[m][n] = {0.f, 0.f, 0.f, 0.f};

    // ---- prologue: tile0 full (8 loads/thr), tile1 B0,B1,A-half0 (6 loads/thr) ----
    {
      char* s0A = smem;            char* s0B = smem + 32768;
      char* s1A = smem + 65536;    char* s1B = s1A + 32768;
      stage_half (Bb, ldb, s0B, 0, tid);
      stage_half (Bb, ldb, s0B, 16384, tid);
      stage_Ahalf(Ab, ldb, s0A, 0, tid);
      stage_Ahalf(Ab, ldb, s0A, 1, tid);
      if (nt > 1) {
        stage_half (Bb + 128, ldb, s1B, 0, tid);
        stage_half (Bb + 128, ldb, s1B, 16384, tid);
        stage_Ahalf(Ab + 128, ldb, s1A, 0, tid);
        asm volatile("s_waitcnt vmcnt(6)" ::: "memory");
      } else {
        asm volatile("s_waitcnt vmcnt(0)" ::: "memory");
      }
      __builtin_amdgcn_s_barrier();
    }

    // ---- main loop: 4 phases per K-tile, counted vmcnt(6), never drain ----
#pragma unroll 1
    for (int t = 0; t < nt; ++t) {
      char* sA = smem + (t & 1) * 65536;
      char* sB = sA + 32768;
      char* oA = smem + ((t & 1) ^ 1) * 65536;
      const char* Ag1 = Ab + (size_t)(t + 1) * 128;
      const char* Ag2 = Ab + (size_t)(t + 2) * 128;
      const char* Bg2 = Bb + (size_t)(t + 2) * 128;

      // B fragments for the whole tile (8 x ds_read_b128), held in regs
      bf16x8 bfr[4][2];
#pragma unroll
      for (int ni = 0; ni < 4; ++ni)
#pragma unroll
        for (int kk = 0; kk < 2; ++kk) {
          const int row = wcol * 64 + ni * 16 + lm;
          bfr[ni][kk] = *(const bf16x8*)(sB + ((row * 128 + kk * 64 + hi16) ^ axor));
        }

      do_phase<0>(acc, bfr, sA, wrow, lm, hi16, axor,
                  [&] { if (t + 1 < nt) stage_Ahalf(Ag1, ldb, oA, 1, tid); });
      __builtin_amdgcn_s_barrier();
      do_phase<1>(acc, bfr, sA, wrow, lm, hi16, axor,
                  [&] { if (t + 2 < nt) stage_half(Bg2, ldb, sB, 0, tid); });
      __builtin_amdgcn_s_barrier();
      do_phase<2>(acc, bfr, sA, wrow, lm, hi16, axor,
                  [&] { if (t + 2 < nt) stage_half(Bg2, ldb, sB, 16384, tid); });
      __builtin_amdgcn_s_barrier();
      do_phase<3>(acc, bfr, sA, wrow, lm, hi16, axor,
                  [&] { if (t + 2 < nt) stage_Ahalf(Ag2, ldb, sA, 0, tid); });
      if (t + 2 < nt)      asm volatile("s_waitcnt vmcnt(6)" ::: "memory");
      else if (t + 1 < nt) asm volatile("s_waitcnt vmcnt(0)" ::: "memory");
      __builtin_amdgcn_s_barrier();
    }

    // ---- epilogue: C/D layout col = lane&15, row = (lane>>4)*4 + r ----
    const int lr = (lane >> 4) * 4;
#pragma unroll
    for (int m = 0; m < 8; ++m) {
      const long row0 = (long)bm * 256 + wrow * 128 + m * 16 + lr;
#pragma unroll
      for (int ni = 0; ni < 4; ++ni) {
        const long col = (long)bn * 256 + wcol * 64 + ni * 16 + lm;
#pragma unroll
        for (int r = 0; r < 4; ++r) {
          const long idx = (row0 + r) * N + col;
          if constexpr (OUT_BF16) ((u16*)Cv)[idx] = f2bf(acc[m][ni][r]);
          else                    ((float*)Cv)[idx] = acc[m][ni][r];
        }
      }
    }
  }
}

// ---------- launch ----------
extern "C" void kernel_launch(void* const* d_in, const int* in_sizes, int n_in,
                              void* d_out, int out_size, void* d_ws, size_t ws_size,
                              hipStream_t stream) {
  const float* x  = (const float*)d_in[0];
  // d_in[1] = Wq (dead), d_in[2] = Wk (dead), d_in[5] = mask (dead)
  const float* Wv = (const float*)d_in[3];
  const float* Wo = (const float*)d_in[4];

  const int M = 16384;   // B*S
  const int D = 4096;    // DIM
  const int R = 1024;    // KV_RANK

  u16* vb   = (u16*)d_ws;
  u16* Wvb  = vb + (size_t)M * R;
  u16* Wofb = Wvb + (size_t)R * D;
  u16* xb   = (u16*)d_out;   // dead by the time GEMM2 writes d_out

  (void)hipFuncSetAttribute((const void*)gemm256<true, 1>,
                            hipFuncAttributeMaxDynamicSharedMemorySize, 131072);
  (void)hipFuncSetAttribute((const void*)gemm256<false, 4>,
                            hipFuncAttributeMaxDynamicSharedMemorySize, 131072);

  prep_all<<<dim3(2048), dim3(256), 0, stream>>>((const float4*)x, Wv, Wo,
                                                 (uint4*)xb, (uint4*)Wvb, (uint4*)Wofb);
  // v = x @ Wv^T   (M=16384, N=1024, K=4096): 256 tiles, 1 rep
  gemm256<true, 1><<<dim3(256), dim3(512), 131072, stream>>>(xb, Wvb, vb, M, R, D);
  // out = v @ Wofold^T (M=16384, N=4096, K=1024): 1024 tiles, persistent 4 reps
  gemm256<false, 4><<<dim3(256), dim3(512), 131072, stream>>>(vb, Wofb, (float*)d_out, M, D, R);
}